// Round 1
// baseline (2113.842 us; speedup 1.0000x reference)
//
#include <hip/hip_runtime.h>

#define VV 50257
#define DD 50
#define TT 1024
#define BB 1024

__device__ __forceinline__ float rl(float v, int lane) {
    return __int_as_float(__builtin_amdgcn_readlane(__float_as_int(v), lane));
}
__device__ __forceinline__ float sigmf(float x) { return 1.0f / (1.0f + __expf(-x)); }
__device__ __forceinline__ float tanhf_fast(float x) {
    float e = __expf(-2.0f * fabsf(x));
    return copysignf((1.0f - e) / (1.0f + e), x);
}

// P1[v][j] = b1[0][j] + sum_d emb[v][d] * kx1[d][j]   (one-time, ~0.5 GFLOP)
__global__ void proj_emb(const float* __restrict__ emb, const float* __restrict__ kx1,
                         const float* __restrict__ b1, float* __restrict__ P1) {
    int j = threadIdx.x;             // 0..95
    int v0 = blockIdx.x * 8;
    #pragma unroll 1
    for (int vv = 0; vv < 8; ++vv) {
        int v = v0 + vv;
        if (v >= VV) return;
        float acc = b1[j];
        #pragma unroll
        for (int d = 0; d < DD; ++d)
            acc += emb[v * DD + d] * kx1[d * 96 + j];
        P1[v * 96 + j] = acc;
    }
}

// One wave per batch row. All weights + both hidden states live in registers.
// Zero LDS, zero barriers: recurrent broadcast = v_readlane from the state reg.
//  - h2[j] lives in lane j (j = 0..63); GRU2 cols for lane j: z=j, r=64+j, h=128+j.
//  - h1[j] lives in lane j (j = 0..31); GRU1 cols: lane j<64 -> col j (z for 0..31,
//    r for 32..63), lanes 0..31 also col 64+j (h). r-preact reaches lane j via
//    __shfl_xor(az, 32). Lanes 32..63 carry garbage h1 that is never readlane'd.
// 4 independent waves per 256-thread block, grid = 256 -> 1 block/CU, 1 wave/SIMD.
__global__ __launch_bounds__(256, 1)
void rnn_main(const int* __restrict__ tokens, const float* __restrict__ P1,
              const float* __restrict__ kh1, const float* __restrict__ b1,
              const float* __restrict__ kx2, const float* __restrict__ kh2,
              const float* __restrict__ b2, const float* __restrict__ wg,
              const float* __restrict__ bg, const float* __restrict__ wd,
              const float* __restrict__ bd, float* __restrict__ out) {
    const int lane = threadIdx.x & 63;
    const int row  = blockIdx.x * 4 + (threadIdx.x >> 6);
    const int l32  = lane & 31;
    const int* __restrict__ trow = tokens + row * TT;

    // ---- persistent per-lane weight columns (≈360 VGPRs) ----
    float w2r[192], w2x[96], w1a[32], w1b[32];
    #pragma unroll
    for (int k = 0; k < 64; ++k) {
        w2r[3*k]   = kh2[k*192 + lane];
        w2r[3*k+1] = kh2[k*192 + 64 + lane];
        w2r[3*k+2] = kh2[k*192 + 128 + lane];
    }
    #pragma unroll
    for (int k = 0; k < 32; ++k) {
        w2x[3*k]   = kx2[k*192 + lane];
        w2x[3*k+1] = kx2[k*192 + 64 + lane];
        w2x[3*k+2] = kx2[k*192 + 128 + lane];
        w1a[k] = kh1[k*96 + lane];
        w1b[k] = (lane < 32) ? kh1[k*96 + 64 + lane] : 0.f;
    }
    const float b2xz = b2[lane],     b2xr = b2[64 + lane],  b2xh = b2[128 + lane];
    const float b2rz = b2[192+lane], b2rr = b2[256 + lane], b2rh = b2[320 + lane];
    const float b1z  = b1[96 + lane];
    const float b1h  = (lane < 32) ? b1[160 + lane] : 0.f;

    float h1 = 0.f, h2 = 0.f;

    // P1 row for step t is prefetched one full iteration ahead.
    int tok1 = trow[1];
    float pz, pr, ph;
    {
        const float* __restrict__ p = P1 + trow[0] * 96;
        pz = p[l32]; pr = p[32 + l32]; ph = p[64 + l32];
    }

    #pragma unroll 1
    for (int t = 0; t < TT; ++t) {
        // prefetch: P1 row for step t+1, token for step t+2
        const float* __restrict__ pn = P1 + tok1 * 96;
        float pzn = pn[l32], prn = pn[32 + l32], phn = pn[64 + l32];
        int tokn = trow[(t + 2 < TT) ? (t + 2) : (TT - 1)];

        // GRU2 recurrent matvec (depends only on h2(t-1) -> issue first for ILP)
        float mz = b2rz, mr = b2rr, mh = b2rh;
        #pragma unroll
        for (int k = 0; k < 64; ++k) {
            float s = rl(h2, k);
            mz += s * w2r[3*k];
            mr += s * w2r[3*k+1];
            mh += s * w2r[3*k+2];
        }
        // GRU1 recurrent matvec
        float az = b1z, ah = b1h;
        #pragma unroll
        for (int k = 0; k < 32; ++k) {
            float s = rl(h1, k);
            az += s * w1a[k];
            ah += s * w1b[k];
        }
        // GRU1 gates -> h1(t)   (meaningful on lanes 0..31)
        float ra  = __shfl_xor(az, 32);
        float z1  = sigmf(pz + az);
        float r1  = sigmf(pr + ra);
        float hh1 = tanhf_fast(ph + r1 * ah);
        h1 = z1 * h1 + (1.f - z1) * hh1;
        // GRU2 input projection from h1(t)
        float xz = b2xz, xr = b2xr, xh = b2xh;
        #pragma unroll
        for (int k = 0; k < 32; ++k) {
            float s = rl(h1, k);
            xz += s * w2x[3*k];
            xr += s * w2x[3*k+1];
            xh += s * w2x[3*k+2];
        }
        // GRU2 gates -> h2(t)
        float z2  = sigmf(xz + mz);
        float r2  = sigmf(xr + mr);
        float hh2 = tanhf_fast(xh + r2 * mh);
        h2 = z2 * h2 + (1.f - z2) * hh2;

        pz = pzn; pr = prn; ph = phn; tok1 = tokn;
    }

    // ---- tail: GLU + dense head, once per wave ----
    // a[c] for c = lane, 64+lane, 128+lane, 192+lane
    float a0 = bg[lane], a1 = bg[64 + lane], a2 = bg[128 + lane], a3 = bg[192 + lane];
    #pragma unroll
    for (int k = 0; k < 64; ++k) {
        float s = rl(h2, k);
        a0 += s * wg[k*256 + lane];
        a1 += s * wg[k*256 + 64 + lane];
        a2 += s * wg[k*256 + 128 + lane];
        a3 += s * wg[k*256 + 192 + lane];
    }
    // GLU: x[i] = a[i] * sigm(a[128+i]); dense: sum_i x[i]*wd[i]
    float g = a0 * sigmf(a2) * wd[lane] + a1 * sigmf(a3) * wd[64 + lane];
    g += __shfl_xor(g, 32); g += __shfl_xor(g, 16); g += __shfl_xor(g, 8);
    g += __shfl_xor(g, 4);  g += __shfl_xor(g, 2);  g += __shfl_xor(g, 1);
    if (lane == 0) out[row] = sigmf(g + bd[0]);
}

extern "C" void kernel_launch(void* const* d_in, const int* in_sizes, int n_in,
                              void* d_out, int out_size, void* d_ws, size_t ws_size,
                              hipStream_t stream) {
    const int*   tokens = (const int*)d_in[0];
    const float* emb = (const float*)d_in[1];
    const float* kx1 = (const float*)d_in[2];
    const float* kh1 = (const float*)d_in[3];
    const float* b1  = (const float*)d_in[4];
    const float* kx2 = (const float*)d_in[5];
    const float* kh2 = (const float*)d_in[6];
    const float* b2  = (const float*)d_in[7];
    const float* wg  = (const float*)d_in[8];
    const float* bg  = (const float*)d_in[9];
    const float* wd  = (const float*)d_in[10];
    const float* bd  = (const float*)d_in[11];
    float* out = (float*)d_out;
    float* P1  = (float*)d_ws;   // needs 50257*96*4 = 19.3 MB of workspace

    proj_emb<<<(VV + 7) / 8, 96, 0, stream>>>(emb, kx1, b1, P1);
    rnn_main<<<BB / 4, 256, 0, stream>>>(tokens, P1, kh1, b1, kx2, kh2, b2,
                                         wg, bg, wd, bd, out);
}

// Round 3
// 1373.528 us; speedup vs baseline: 1.5390x; 1.5390x over previous
//
#include <hip/hip_runtime.h>

#define VV 50257
#define DD 50
#define TT 1024
#define BB 1024

__device__ __forceinline__ float rl(float v, int lane) {
    return __int_as_float(__builtin_amdgcn_readlane(__float_as_int(v), lane));
}
__device__ __forceinline__ float sigmf(float x) { return 1.0f / (1.0f + __expf(-x)); }
__device__ __forceinline__ float tanhf_fast(float x) {
    float e = __expf(-2.0f * fabsf(x));
    return copysignf((1.0f - e) / (1.0f + e), x);
}

// P1[v][j] = b1[0][j] + sum_d emb[v][d] * kx1[d][j]   (one-time, ~0.5 GFLOP)
__global__ void proj_emb(const float* __restrict__ emb, const float* __restrict__ kx1,
                         const float* __restrict__ b1, float* __restrict__ P1) {
    int j = threadIdx.x;             // 0..95
    int v0 = blockIdx.x * 8;
    #pragma unroll 1
    for (int vv = 0; vv < 8; ++vv) {
        int v = v0 + vv;
        if (v >= VV) return;
        float acc = b1[j];
        #pragma unroll
        for (int d = 0; d < DD; ++d)
            acc += emb[v * DD + d] * kx1[d * 96 + j];
        P1[v * 96 + j] = acc;
    }
}

// Two waves per row, producer/consumer with 1-step skew, ONE barrier per step.
//  Wave B (wv=1): GRU1 recurrence + GRU2 input projection (kh1 64 + kx2 96 regs).
//    At iter t it computes h1(t+1) and x(t+1)=h1(t+1)·kx2+b2[0], writes float4
//    {xz,xr,xh} to LDS ring slot (t+1)&3.
//  Wave A (wv=0): GRU2 recurrence (kh2 192 regs). At iter t it computes
//    m(t)=h2(t-1)·kh2+b2[1] pre-barrier, then post-barrier reads x(t) from slot
//    t&3 and forms h2(t).
//  Ring depth 4 + one barrier/iter: slot s is rewritten 4 iters later, with an
//  intervening barrier ordering the consumer's read before the rewrite.
//  Weight arrays of the two roles are UNIONED into wreg[192] so regalloc sees
//  max(192,160), keeping both waves <= ~230 VGPRs (no spill, no AGPR copies).
//  Per-lane layouts identical to the round-1 kernel that passed (absmax 0).
__global__ __launch_bounds__(128, 2)
void rnn_main(const int* __restrict__ tokens, const float* __restrict__ P1,
              const float* __restrict__ kh1, const float* __restrict__ b1,
              const float* __restrict__ kx2, const float* __restrict__ kh2,
              const float* __restrict__ b2, const float* __restrict__ wg,
              const float* __restrict__ bg, const float* __restrict__ wd,
              const float* __restrict__ bd, float* __restrict__ out) {
    const int lane = threadIdx.x & 63;
    const int wv   = threadIdx.x >> 6;        // 0 = consumer (GRU2), 1 = producer
    const int row  = blockIdx.x;
    const int l32  = lane & 31;
    const int* __restrict__ trow = tokens + row * TT;

    __shared__ float4 xbuf[4][64];            // ring of x-triples

    float wreg[192];
    float bias0, bias1, bias2, bias3 = 0.f, bias4 = 0.f;

    if (wv == 0) {
        // kh2 columns: z=lane, r=64+lane, h=128+lane
        #pragma unroll
        for (int k = 0; k < 64; ++k) {
            wreg[3 * k]     = kh2[k * 192 + lane];
            wreg[3 * k + 1] = kh2[k * 192 + 64 + lane];
            wreg[3 * k + 2] = kh2[k * 192 + 128 + lane];
        }
        bias0 = b2[192 + lane];               // recurrent biases b2[1]
        bias1 = b2[256 + lane];
        bias2 = b2[320 + lane];
    } else {
        // kh1: col lane (z for lane<32, r for lane>=32); h-col 64+lane for lane<32
        #pragma unroll
        for (int k = 0; k < 32; ++k) {
            wreg[k]      = kh1[k * 96 + lane];
            wreg[32 + k] = (lane < 32) ? kh1[k * 96 + 64 + lane] : 0.f;
            wreg[64 + 3 * k] = kx2[k * 192 + lane];
            wreg[65 + 3 * k] = kx2[k * 192 + 64 + lane];
            wreg[66 + 3 * k] = kx2[k * 192 + 128 + lane];
        }
        bias0 = b1[96 + lane];                              // GRU1 recurrent z/r
        bias1 = (lane < 32) ? b1[160 + lane] : 0.f;         // GRU1 recurrent h
        bias2 = b2[lane];                                   // input-proj biases b2[0]
        bias3 = b2[64 + lane];
        bias4 = b2[128 + lane];
    }

    float h1 = 0.f, h2 = 0.f;
    float pz = 0.f, pr = 0.f, ph = 0.f;
    if (wv == 1) {                            // p-triple for GRU1 step 0
        const float* __restrict__ p = P1 + trow[0] * 96;
        pz = p[l32]; pr = p[32 + l32]; ph = p[64 + l32];
    }

    // iter t: B produces x(t+1) (t=-1 produces x(0)); barrier; A consumes x(t).
    #pragma unroll 1
    for (int t = -1; t < TT; ++t) {
        float mz = 0.f, mr = 0.f, mh = 0.f;
        if (wv == 0) {
            if (t >= 0) {
                mz = bias0; mr = bias1; mh = bias2;
                #pragma unroll
                for (int k = 0; k < 64; ++k) {
                    float s = rl(h2, k);
                    mz += s * wreg[3 * k];
                    mr += s * wreg[3 * k + 1];
                    mh += s * wreg[3 * k + 2];
                }
            }
        } else if (t + 1 < TT) {
            // prefetch p(t+2) for next iteration
            int tk = trow[(t + 2 < TT) ? (t + 2) : (TT - 1)];
            const float* __restrict__ pn = P1 + tk * 96;
            float pzn = pn[l32], prn = pn[32 + l32], phn = pn[64 + l32];
            // GRU1 recurrence: h1(t) -> h1(t+1)
            float az = bias0, ah = bias1;
            #pragma unroll
            for (int k = 0; k < 32; ++k) {
                float s = rl(h1, k);
                az += s * wreg[k];
                ah += s * wreg[32 + k];
            }
            float ra  = __shfl_xor(az, 32);   // r-preact to lanes 0..31
            float z1  = sigmf(pz + az);
            float r1  = sigmf(pr + ra);
            float hh1 = tanhf_fast(ph + r1 * ah);
            h1 = z1 * h1 + (1.f - z1) * hh1;
            // GRU2 input projection x(t+1) = h1(t+1)·kx2 + b2[0]
            float xz = bias2, xr = bias3, xh = bias4;
            #pragma unroll
            for (int k = 0; k < 32; ++k) {
                float s = rl(h1, k);
                xz += s * wreg[64 + 3 * k];
                xr += s * wreg[65 + 3 * k];
                xh += s * wreg[66 + 3 * k];
            }
            xbuf[(t + 1) & 3][lane] = make_float4(xz, xr, xh, 0.f);
            pz = pzn; pr = prn; ph = phn;
        }
        __syncthreads();
        if (wv == 0 && t >= 0) {
            float4 x  = xbuf[t & 3][lane];
            float z2  = sigmf(x.x + mz);
            float r2  = sigmf(x.y + mr);
            float hh2 = tanhf_fast(x.z + r2 * mh);
            h2 = z2 * h2 + (1.f - z2) * hh2;
        }
    }

    // ---- tail: GLU + dense head, wave A only (holds h2) ----
    if (wv == 0) {
        float a0 = bg[lane], a1 = bg[64 + lane], a2 = bg[128 + lane], a3 = bg[192 + lane];
        #pragma unroll
        for (int k = 0; k < 64; ++k) {
            float s = rl(h2, k);
            a0 += s * wg[k * 256 + lane];
            a1 += s * wg[k * 256 + 64 + lane];
            a2 += s * wg[k * 256 + 128 + lane];
            a3 += s * wg[k * 256 + 192 + lane];
        }
        float g = a0 * sigmf(a2) * wd[lane] + a1 * sigmf(a3) * wd[64 + lane];
        g += __shfl_xor(g, 32); g += __shfl_xor(g, 16); g += __shfl_xor(g, 8);
        g += __shfl_xor(g, 4);  g += __shfl_xor(g, 2);  g += __shfl_xor(g, 1);
        if (lane == 0) out[row] = sigmf(g + bd[0]);
    }
}

extern "C" void kernel_launch(void* const* d_in, const int* in_sizes, int n_in,
                              void* d_out, int out_size, void* d_ws, size_t ws_size,
                              hipStream_t stream) {
    const int*   tokens = (const int*)d_in[0];
    const float* emb = (const float*)d_in[1];
    const float* kx1 = (const float*)d_in[2];
    const float* kh1 = (const float*)d_in[3];
    const float* b1  = (const float*)d_in[4];
    const float* kx2 = (const float*)d_in[5];
    const float* kh2 = (const float*)d_in[6];
    const float* b2  = (const float*)d_in[7];
    const float* wg  = (const float*)d_in[8];
    const float* bg  = (const float*)d_in[9];
    const float* wd  = (const float*)d_in[10];
    const float* bd  = (const float*)d_in[11];
    float* out = (float*)d_out;
    float* P1  = (float*)d_ws;   // needs 50257*96*4 = 19.3 MB of workspace

    proj_emb<<<(VV + 7) / 8, 96, 0, stream>>>(emb, kx1, b1, P1);
    rnn_main<<<BB, 128, 0, stream>>>(tokens, P1, kh1, b1, kx2, kh2, b2,
                                     wg, bg, wd, bd, out);
}